// Round 9
// baseline (55.405 us; speedup 1.0000x reference)
//
#include <hip/hip_runtime.h>

#define HALFB 0.5f
#define CAPB  0.1f

typedef float vf4 __attribute__((ext_vector_type(4)));

__device__ __forceinline__ float clip05(float z) {
    return fminf(fmaxf(z, -HALFB), HALFB);   // v_med3_f32
}

// 4-lane xor-reduce via DPP quad_perm (pure VALU, no LDS pipe).
template <int CTRL>
__device__ __forceinline__ float dppf(float v) {
    return __int_as_float(__builtin_amdgcn_update_dpp(
        __float_as_int(v), __float_as_int(v), CTRL, 0xF, 0xF, false));
}
__device__ __forceinline__ float red4f(float v) {
    v += dppf<0xB1>(v); v += dppf<0x4E>(v); return v;
}
__device__ __forceinline__ float min4f(float v) {
    v = fminf(v, dppf<0xB1>(v)); v = fminf(v, dppf<0x4E>(v)); return v;
}
__device__ __forceinline__ float max4f(float v) {
    v = fmaxf(v, dppf<0xB1>(v)); v = fmaxf(v, dppf<0x4E>(v)); return v;
}

// Solve one 16-row group held in v[8] (4 lanes/row, interleaved ownership:
// lane q owns float4s {q, q+4, ..., q+28} -> dense 64B lines per instruction).
// Newton math identical to rounds 2-8 (proven absmax 1.95e-3).
__device__ __forceinline__ void solve_store(const float4 (&v)[8], float4* po)
{
    float s0a = 0.f, s0b = 0.f, s0c = 0.f, s0d = 0.f;
    float naa = 0.f, nab = 0.f, nac = 0.f, nad = 0.f;
    float mna = 3.0e38f, mnb = 3.0e38f, mxa = -3.0e38f, mxb = -3.0e38f;
    #pragma unroll
    for (int j = 0; j < 8; ++j) {
        s0a += clip05(v[j].x); s0b += clip05(v[j].y);
        s0c += clip05(v[j].z); s0d += clip05(v[j].w);
        naa += (fabsf(v[j].x) < HALFB) ? 1.f : 0.f;
        nab += (fabsf(v[j].y) < HALFB) ? 1.f : 0.f;
        nac += (fabsf(v[j].z) < HALFB) ? 1.f : 0.f;
        nad += (fabsf(v[j].w) < HALFB) ? 1.f : 0.f;
        mna = fminf(mna, fminf(v[j].x, v[j].y));
        mnb = fminf(mnb, fminf(v[j].z, v[j].w));
        mxa = fmaxf(mxa, fmaxf(v[j].x, v[j].y));
        mxb = fmaxf(mxb, fmaxf(v[j].z, v[j].w));
    }
    float g  = red4f((s0a + s0b) + (s0c + s0d));
    float na = red4f((naa + nab) + (nac + nad));
    const float vmn = min4f(fminf(mna, mnb));
    const float vmx = max4f(fmaxf(mxa, mxb));

    const float t = fminf(fmaxf(g, -CAPB), CAPB);
    float lo  = vmn - (HALFB + CAPB);
    float hi  = vmx + (HALFB + CAPB);
    float lam = 0.f;

    for (int it = 0; it < 20; ++it) {
        if (fabsf(g - t) <= 1e-4f) break;     // final division heals residual
        if (g > t) lo = lam; else hi = lam;   // g decreasing in lam
        float ln;
        if (na > 0.f) {
            ln = lam + (g - t) * __builtin_amdgcn_rcpf(na);
            if (!(ln > lo && ln < hi)) ln = 0.5f * (lo + hi);
        } else {
            ln = 0.5f * (lo + hi);
        }
        if (ln == lam) break;
        lam = ln;

        float ga = 0.f, gb = 0.f, gc = 0.f, gd = 0.f;
        float pa = 0.f, pb = 0.f, pc = 0.f, pd = 0.f;
        #pragma unroll
        for (int j = 0; j < 8; ++j) {
            const float z0 = v[j].x - lam, z1 = v[j].y - lam;
            const float z2 = v[j].z - lam, z3 = v[j].w - lam;
            ga += clip05(z0); gb += clip05(z1);
            gc += clip05(z2); gd += clip05(z3);
            pa += (fabsf(z0) < HALFB) ? 1.f : 0.f;
            pb += (fabsf(z1) < HALFB) ? 1.f : 0.f;
            pc += (fabsf(z2) < HALFB) ? 1.f : 0.f;
            pd += (fabsf(z3) < HALFB) ? 1.f : 0.f;
        }
        g  = red4f((ga + gb) + (gc + gd));
        na = red4f((pa + pb) + (pc + pd));
    }

    const float lam_f = (na > 0.f) ? lam + (g - t) / na : lam;

    // Non-temporal stores: output is never re-read by the kernel; keep it out
    // of L2/L3 so the 134MB input stays L3-resident across replays.
    #pragma unroll
    for (int j = 0; j < 8; ++j) {
        float4 r = make_float4(clip05(v[j].x - lam_f), clip05(v[j].y - lam_f),
                               clip05(v[j].z - lam_f), clip05(v[j].w - lam_f));
        __builtin_nontemporal_store(*(const vf4*)&r, (vf4*)(po + (j << 2)));
    }
}

// 2048 blocks x 4 waves; each wave runs TWO 16-row groups, software-pipelined:
// group 1's loads are issued before group 0's solve (~1500 cyc of VALU work
// hides the L3/HBM latency). Groups strided by nwaves so addressing stays
// line-dense per wave.
__global__ __launch_bounds__(256, 4) void proj_kernel(
    const float* __restrict__ x, float* __restrict__ out, int nrows)
{
    const int lane   = threadIdx.x & 63;
    const int q      = lane & 3;
    const int rsub   = lane >> 2;
    const int wid    = (blockIdx.x << 2) | (threadIdx.x >> 6);
    const int nwaves = gridDim.x << 2;             // 8192

    const int row0 = ((wid)          << 4) | rsub;
    const int row1 = ((wid + nwaves) << 4) | rsub;

    const float4* __restrict__ px = (const float4*)x;
    float4*       __restrict__ po = (float4*)out;

    const float4* p0 = px + ((size_t)row0 << 5) + q;
    const float4* p1 = px + ((size_t)row1 << 5) + q;

    float4 v0[8], v1[8];
    #pragma unroll
    for (int j = 0; j < 8; ++j) v0[j] = p0[j << 2];
    #pragma unroll
    for (int j = 0; j < 8; ++j) v1[j] = p1[j << 2];   // prefetch: hides under solve 0

    solve_store(v0, po + ((size_t)row0 << 5) + q);
    solve_store(v1, po + ((size_t)row1 << 5) + q);
}

extern "C" void kernel_launch(void* const* d_in, const int* in_sizes, int n_in,
                              void* d_out, int out_size, void* d_ws, size_t ws_size,
                              hipStream_t stream) {
    const float* x = (const float*)d_in[0];
    float* out     = (float*)d_out;
    const int nrows = out_size / 128;                 // 262144
    // per block: 4 waves x 16 rows x 2 groups = 128 rows
    const int grid  = (nrows + 127) / 128;            // 2048
    hipLaunchKernelGGL(proj_kernel, dim3(grid), dim3(256), 0, stream, x, out, nrows);
}

// Round 10
// 45.373 us; speedup vs baseline: 1.2211x; 1.2211x over previous
//
#include <hip/hip_runtime.h>

#define HALFB 0.5f
#define CAPB  0.1f

__device__ __forceinline__ float clip05(float z) {
    return fminf(fmaxf(z, -HALFB), HALFB);   // v_med3_f32
}

// 8-lane xor-reduce via DPP (pure VALU, no LDS pipe).
// 0xB1 = quad_perm xor1, 0x4E = quad_perm xor2, 0x141 = row_half_mirror
// (swaps the two 4-lane halves of each 8-lane group; valid as the final stage
// because after xor1+xor2 each 4-lane half holds a uniform partial sum).
template <int CTRL>
__device__ __forceinline__ float dppf(float v) {
    return __int_as_float(__builtin_amdgcn_update_dpp(
        __float_as_int(v), __float_as_int(v), CTRL, 0xF, 0xF, false));
}
__device__ __forceinline__ float red8f(float v) {
    v += dppf<0xB1>(v); v += dppf<0x4E>(v); v += dppf<0x141>(v); return v;
}
__device__ __forceinline__ float min8f(float v) {
    v = fminf(v, dppf<0xB1>(v)); v = fminf(v, dppf<0x4E>(v));
    v = fminf(v, dppf<0x141>(v)); return v;
}
__device__ __forceinline__ float max8f(float v) {
    v = fmaxf(v, dppf<0xB1>(v)); v = fmaxf(v, dppf<0x4E>(v));
    v = fmaxf(v, dppf<0x141>(v)); return v;
}

// 8 lanes per row, 16 elems (4 x float4) per lane; interleaved ownership:
// lane q owns float4s {q, q+8, q+16, q+24} -> each 8-lane group covers a dense
// 128B (2-line) span per instruction; 16 lines/wave-instr (same as round 8).
// Smaller quantum: 8 rows/wave, 32768 waves -> deeper+desynchronized TLP.
// Newton math identical to rounds 2-9 (proven absmax 1.95e-3).
__global__ __launch_bounds__(256, 4) void proj_kernel(
    const float* __restrict__ x, float* __restrict__ out, int nrows)
{
    const int lane = threadIdx.x & 63;
    const int wid  = (blockIdx.x << 2) | (threadIdx.x >> 6);
    const int q    = lane & 7;                     // eighth of row
    int row = (wid << 3) | (lane >> 3);            // 8 rows per wave
    if (row >= nrows) row = nrows - 1;             // grid divides exactly

    const float4* __restrict__ px = (const float4*)x  + ((size_t)row << 5) + q;
    float4*       __restrict__ po = (float4*)out      + ((size_t)row << 5) + q;

    float4 v[4];
    #pragma unroll
    for (int j = 0; j < 4; ++j) v[j] = px[j << 3];   // stride 8 float4 = 128B

    // init sweep: 4-way partial trees for s0 / n_act / min / max
    float s0a = 0.f, s0b = 0.f, s0c = 0.f, s0d = 0.f;
    float naa = 0.f, nab = 0.f, nac = 0.f, nad = 0.f;
    float mna = 3.0e38f, mnb = 3.0e38f, mxa = -3.0e38f, mxb = -3.0e38f;
    #pragma unroll
    for (int j = 0; j < 4; ++j) {
        s0a += clip05(v[j].x); s0b += clip05(v[j].y);
        s0c += clip05(v[j].z); s0d += clip05(v[j].w);
        naa += (fabsf(v[j].x) < HALFB) ? 1.f : 0.f;
        nab += (fabsf(v[j].y) < HALFB) ? 1.f : 0.f;
        nac += (fabsf(v[j].z) < HALFB) ? 1.f : 0.f;
        nad += (fabsf(v[j].w) < HALFB) ? 1.f : 0.f;
        mna = fminf(mna, fminf(v[j].x, v[j].y));
        mnb = fminf(mnb, fminf(v[j].z, v[j].w));
        mxa = fmaxf(mxa, fmaxf(v[j].x, v[j].y));
        mxb = fmaxf(mxb, fmaxf(v[j].z, v[j].w));
    }
    float g  = red8f((s0a + s0b) + (s0c + s0d));
    float na = red8f((naa + nab) + (nac + nad));
    const float vmn = min8f(fminf(mna, mnb));
    const float vmx = max8f(fmaxf(mxa, mxb));

    const float t = fminf(fmaxf(g, -CAPB), CAPB);
    float lo  = vmn - (HALFB + CAPB);
    float hi  = vmx + (HALFB + CAPB);
    float lam = 0.f;

    for (int it = 0; it < 20; ++it) {
        if (fabsf(g - t) <= 1e-4f) break;     // final division heals residual
        if (g > t) lo = lam; else hi = lam;   // g decreasing in lam
        float ln;
        if (na > 0.f) {
            ln = lam + (g - t) * __builtin_amdgcn_rcpf(na);
            if (!(ln > lo && ln < hi)) ln = 0.5f * (lo + hi);
        } else {
            ln = 0.5f * (lo + hi);
        }
        if (ln == lam) break;
        lam = ln;

        float ga = 0.f, gb = 0.f, gc = 0.f, gd = 0.f;
        float pa = 0.f, pb = 0.f, pc = 0.f, pd = 0.f;
        #pragma unroll
        for (int j = 0; j < 4; ++j) {
            const float z0 = v[j].x - lam, z1 = v[j].y - lam;
            const float z2 = v[j].z - lam, z3 = v[j].w - lam;
            ga += clip05(z0); gb += clip05(z1);
            gc += clip05(z2); gd += clip05(z3);
            pa += (fabsf(z0) < HALFB) ? 1.f : 0.f;
            pb += (fabsf(z1) < HALFB) ? 1.f : 0.f;
            pc += (fabsf(z2) < HALFB) ? 1.f : 0.f;
            pd += (fabsf(z3) < HALFB) ? 1.f : 0.f;
        }
        g  = red8f((ga + gb) + (gc + gd));
        na = red8f((pa + pb) + (pc + pd));
    }

    // exact closed form over the active set (== reference's last step)
    const float lam_f = (na > 0.f) ? lam + (g - t) / na : lam;

    #pragma unroll
    for (int j = 0; j < 4; ++j) {
        po[j << 3] = make_float4(clip05(v[j].x - lam_f), clip05(v[j].y - lam_f),
                                 clip05(v[j].z - lam_f), clip05(v[j].w - lam_f));
    }
}

extern "C" void kernel_launch(void* const* d_in, const int* in_sizes, int n_in,
                              void* d_out, int out_size, void* d_ws, size_t ws_size,
                              hipStream_t stream) {
    const float* x = (const float*)d_in[0];
    float* out     = (float*)d_out;
    const int nrows = out_size / 128;             // 262144
    // per block: 4 waves x 8 rows = 32 rows
    const int grid  = (nrows + 31) / 32;          // 8192 blocks
    hipLaunchKernelGGL(proj_kernel, dim3(grid), dim3(256), 0, stream, x, out, nrows);
}